// Round 1
// baseline (271.314 us; speedup 1.0000x reference)
//
#include <hip/hip_runtime.h>
#include <math.h>

// SoftKConv: h = feat@W; per node: gather k=32 neighbor rows of h, pairwise
// distances via Gram (MFMA bf16x3 fp32-emulation), weighted medoid cost,
// softmax -> weighted combination of neighbor embeddings.

typedef __attribute__((ext_vector_type(8)))  short  short8;   // 8 bf16 in 4 VGPRs
typedef __attribute__((ext_vector_type(16))) float  f32x16;   // MFMA 32x32 accumulator

#define NK   32
#define DIM  128
#define FKS  132   // fk LDS row stride (pad 4 floats: breaks 32-bank aliasing, keeps 16B align)

static __device__ __forceinline__ short f2bf_rne(float x) {
    union { float f; unsigned u; } v; v.f = x;
    unsigned r = v.u + 0x7FFFu + ((v.u >> 16) & 1u);
    return (short)(r >> 16);
}
static __device__ __forceinline__ float bf2f(short b) {
    union { float f; unsigned u; } v; v.u = ((unsigned)(unsigned short)b) << 16;
    return v.f;
}

// ---------------- Kernel 1: h = feat @ W  (N x 128) @ (128 x 128) ----------
__global__ __launch_bounds__(256) void gemm128(
    const float* __restrict__ A, const float* __restrict__ W,
    float* __restrict__ H, int n)
{
    __shared__ __align__(16) float sW[32][132];  // K-chunk of W, row-major
    __shared__ __align__(16) float sF[64][36];   // 64 rows x 32 K-chunk of feat

    const int t  = threadIdx.x;
    const int r0 = blockIdx.x * 64;
    const int tc = t & 15;    // col group: 8 cols
    const int tr = t >> 4;    // row group: 4 rows

    float acc[4][8];
#pragma unroll
    for (int i = 0; i < 4; ++i)
#pragma unroll
        for (int j = 0; j < 8; ++j) acc[i][j] = 0.0f;

    for (int ck = 0; ck < 4; ++ck) {
        // stage W chunk: 32 x 128
#pragma unroll
        for (int i = 0; i < 4; ++i) {
            int e  = t + i * 256;          // 0..1023 float4s
            int wr = e >> 5, wc = (e & 31) << 2;
            *reinterpret_cast<float4*>(&sW[wr][wc]) =
                *reinterpret_cast<const float4*>(W + (ck * 32 + wr) * 128 + wc);
        }
        // stage feat chunk: 64 x 32
#pragma unroll
        for (int i = 0; i < 2; ++i) {
            int e  = t + i * 256;          // 0..511 float4s
            int fr = e >> 3, fc = (e & 7) << 2;
            int gr = r0 + fr;
            float4 v = make_float4(0.f, 0.f, 0.f, 0.f);
            if (gr < n)
                v = *reinterpret_cast<const float4*>(A + (size_t)gr * 128 + ck * 32 + fc);
            *reinterpret_cast<float4*>(&sF[fr][fc]) = v;
        }
        __syncthreads();

#pragma unroll
        for (int c = 0; c < 32; ++c) {
            float b[8];
            *reinterpret_cast<float4*>(&b[0]) = *reinterpret_cast<const float4*>(&sW[c][tc * 8]);
            *reinterpret_cast<float4*>(&b[4]) = *reinterpret_cast<const float4*>(&sW[c][tc * 8 + 4]);
#pragma unroll
            for (int i = 0; i < 4; ++i) {
                float a = sF[tr * 4 + i][c];
#pragma unroll
                for (int j = 0; j < 8; ++j) acc[i][j] = fmaf(a, b[j], acc[i][j]);
            }
        }
        __syncthreads();
    }

#pragma unroll
    for (int i = 0; i < 4; ++i) {
        int gr = r0 + tr * 4 + i;
        if (gr < n) {
            float4 v0 = {acc[i][0], acc[i][1], acc[i][2], acc[i][3]};
            float4 v1 = {acc[i][4], acc[i][5], acc[i][6], acc[i][7]};
            *reinterpret_cast<float4*>(H + (size_t)gr * 128 + tc * 8)     = v0;
            *reinterpret_cast<float4*>(H + (size_t)gr * 128 + tc * 8 + 4) = v1;
        }
    }
}

// ---------------- Kernel 2: per-node soft medoid, 1 wave per node ----------
__global__ __launch_bounds__(64) void softk(
    const float* __restrict__ h, const float* __restrict__ bias,
    const float* __restrict__ tkw, const int* __restrict__ idx,
    float* __restrict__ out, int n)
{
    __shared__ __align__(16) float fk[NK][FKS];      // gathered rows, fp32
    __shared__ float dist[NK][NK + 1];
    __shared__ float sq[NK];
    __shared__ float wsh[NK];
    __shared__ float rsh[NK];
    __shared__ int   idxs[NK];
    __shared__ int   mks[NK];

    const int node = blockIdx.x;
    const int lane = threadIdx.x;

    if (lane < NK) {
        int id   = idx[(size_t)node * NK + lane];
        int mk   = (id < 0) ? 1 : 0;
        idxs[lane] = mk ? 0 : id;
        mks[lane]  = mk;
        wsh[lane]  = mk ? 0.0f : tkw[(size_t)node * NK + lane];
    }
    __syncthreads();

    // gather 32 rows x 128 floats (1024 float4s, 16 iterations)
#pragma unroll
    for (int it = 0; it < 16; ++it) {
        int e  = it * 64 + lane;
        int r  = e >> 5;
        int c  = (e & 31) << 2;
        float4 v = *reinterpret_cast<const float4*>(h + (size_t)idxs[r] * DIM + c);
        *reinterpret_cast<float4*>(&fk[r][c]) = v;
    }
    __syncthreads();

    // gram = fk @ fk^T via mfma_f32_32x32x16_bf16, bf16x3 emulation.
    // A and B fragments are identical: lane holds fk[lane&31][k0 + j], j=0..7
    const int row   = lane & 31;
    const int khalf = (lane >> 5) * 8;

    f32x16 acc = {0.f,0.f,0.f,0.f,0.f,0.f,0.f,0.f,0.f,0.f,0.f,0.f,0.f,0.f,0.f,0.f};
#pragma unroll
    for (int s = 0; s < 8; ++s) {
        int k0 = s * 16 + khalf;
        float4 p0 = *reinterpret_cast<const float4*>(&fk[row][k0]);
        float4 p1 = *reinterpret_cast<const float4*>(&fk[row][k0 + 4]);
        float x[8] = {p0.x, p0.y, p0.z, p0.w, p1.x, p1.y, p1.z, p1.w};
        short8 hi, lo;
#pragma unroll
        for (int j = 0; j < 8; ++j) {
            short hb = f2bf_rne(x[j]);
            hi[j] = hb;
            lo[j] = f2bf_rne(x[j] - bf2f(hb));
        }
        acc = __builtin_amdgcn_mfma_f32_32x32x16_bf16(hi, hi, acc, 0, 0, 0);
        acc = __builtin_amdgcn_mfma_f32_32x32x16_bf16(hi, lo, acc, 0, 0, 0);
        acc = __builtin_amdgcn_mfma_f32_32x32x16_bf16(lo, hi, acc, 0, 0, 0);
    }

    // C/D layout: col = lane&31, rowD = (reg&3) + 8*(reg>>2) + 4*(lane>>5)
    const int col = row;
#pragma unroll
    for (int reg = 0; reg < 16; ++reg) {
        int rD = (reg & 3) + 8 * (reg >> 2) + 4 * (lane >> 5);
        if (rD == col) sq[col] = acc[reg];
    }
    __syncthreads();

    // dist[rD][col] = sqrt(max(sq[rD]+sq[col]-2*gram, 0)); 0 if d2 <= 0.
    // (pair-mask zeroing is unnecessary: masked m has w=0, masked k gets BIG)
#pragma unroll
    for (int reg = 0; reg < 16; ++reg) {
        int rD = (reg & 3) + 8 * (reg >> 2) + 4 * (lane >> 5);
        float d2 = sq[rD] + sq[col] - 2.0f * acc[reg];
        d2 = fmaxf(d2, 0.0f);
        dist[rD][col] = (d2 > 0.0f) ? sqrtf(d2) : 0.0f;
    }
    __syncthreads();

    // dagg, softmax, weight correction in lanes 0..31
    if (lane < NK) {
        float s = 0.0f;
#pragma unroll
        for (int m = 0; m < NK; ++m) s = fmaf(wsh[m], dist[lane][m], s);
        if (mks[lane] || !isfinite(s)) s = 3.4028235e38f;

        float x  = -s;
        float mx = x;
#pragma unroll
        for (int o = 16; o > 0; o >>= 1) mx = fmaxf(mx, __shfl_xor(mx, o, 32));
        float e  = __expf(x - mx);
        float se = e;
#pragma unroll
        for (int o = 16; o > 0; o >>= 1) se += __shfl_xor(se, o, 32);
        float r = e / se;
        r *= wsh[lane];
        float sr = r;
#pragma unroll
        for (int o = 16; o > 0; o >>= 1) sr += __shfl_xor(sr, o, 32);
        r = r / sr;
        if (mks[lane]) r = 0.0f;
        rsh[lane] = r;
    }
    __syncthreads();

    // out[node][d] = sum_k r[k] * fk[k][d] + bias[d]; 2 cols per lane
    const int d0 = lane, d1 = lane + 64;
    float o0 = 0.0f, o1 = 0.0f;
#pragma unroll
    for (int k = 0; k < NK; ++k) {
        float rk = rsh[k];
        o0 = fmaf(rk, fk[k][d0], o0);
        o1 = fmaf(rk, fk[k][d1], o1);
    }
    size_t base = (size_t)node * DIM;
    out[base + d0] = o0 + bias[d0];
    out[base + d1] = o1 + bias[d1];
}

extern "C" void kernel_launch(void* const* d_in, const int* in_sizes, int n_in,
                              void* d_out, int out_size, void* d_ws, size_t ws_size,
                              hipStream_t stream) {
    const float* feat = (const float*)d_in[0];
    const float* W    = (const float*)d_in[1];
    const float* bias = (const float*)d_in[2];
    const float* tkw  = (const float*)d_in[3];
    const int*   idx  = (const int*)d_in[4];
    float* out = (float*)d_out;
    float* h   = (float*)d_ws;              // needs N*128*4 = 25.6 MB of ws

    const int n = in_sizes[0] / DIM;        // 50000
    const int gblocks = (n + 63) / 64;
    gemm128<<<gblocks, 256, 0, stream>>>(feat, W, h, n);
    softk<<<n, 64, 0, stream>>>(h, bias, tkw, idx, out, n);
}